// Round 13
// baseline (326.043 us; speedup 1.0000x reference)
//
#include <hip/hip_runtime.h>
#include <hip/hip_bf16.h>
#include <hip/hip_fp16.h>
#include <math.h>

#define EPB 8192   // edges per partition block (PB = ceil(nE/EPB) must be <= 256)
#define BPB 256    // nodes per bucket (NB <= 512)

typedef _Float16 v8h __attribute__((ext_vector_type(8)));
typedef float v4f __attribute__((ext_vector_type(4)));

// ---------------- wave helpers (wave = 64 on gfx950) ----------------
__device__ inline float sum16(float v) {  // reduce within 16-lane groups
#pragma unroll
  for (int off = 1; off < 16; off <<= 1) v += __shfl_xor(v, off);
  return v;
}

// load 8 consecutive values as 8 halves (16B)
__device__ inline uint4 load8h(const float* p) {
  float4 a = *(const float4*)p;
  float4 b = *(const float4*)(p + 4);
  union { __half2 h[4]; uint4 u; } pk;
  pk.h[0] = __floats2half2_rn(a.x, a.y);
  pk.h[1] = __floats2half2_rn(a.z, a.w);
  pk.h[2] = __floats2half2_rn(b.x, b.y);
  pk.h[3] = __floats2half2_rn(b.z, b.w);
  return pk.u;
}
__device__ inline uint4 load8h(const __half* p) { return *(const uint4*)p; }

// ---------------- partition body: block-local hist + scan + counting sort ----------------
__device__ inline void psort_body(const int* __restrict__ ei, int* __restrict__ blkoff,
                                  unsigned* __restrict__ part, char* smraw,
                                  int p, int t, int nE, int n, int NB) {
  int* hist = (int*)smraw;                 // 512
  int* sA = hist + 512;                    // 512
  int* sB = sA + 512;                      // 512
  int* cur = sB + 512;                     // 512
  unsigned* buf = (unsigned*)(cur + 512);  // 8192 (32 KB) -> total 40 KB

  for (int i = t; i < 512; i += 256) hist[i] = 0;
  __syncthreads();
  int e0 = p * EPB;
  int e1 = min(e0 + EPB, nE);
  for (int i = e0 + t; i < e1; i += 256) {
    int d = ei[nE + i];
    if ((unsigned)d < (unsigned)n) atomicAdd(&hist[d >> 8], 1);
  }
  __syncthreads();
  for (int i = t; i < 512; i += 256) sA[i] = hist[i];
  __syncthreads();
  int* src = sA;
  int* dst = sB;
  for (int off = 1; off < 512; off <<= 1) {
    for (int i = t; i < 512; i += 256) {
      int v = src[i];
      if (i >= off) v += src[i - off];
      dst[i] = v;
    }
    __syncthreads();
    int* tmp = src; src = dst; dst = tmp;
  }
  int* bo = blkoff + (size_t)p * (NB + 1);
  for (int i = t; i < NB; i += 256) {
    int excl = (i == 0) ? 0 : src[i - 1];
    bo[i] = excl;
    cur[i] = excl;
  }
  if (t == 0) bo[NB] = src[NB - 1];
  __syncthreads();
  for (int i = e0 + t; i < e1; i += 256) {
    int d = ei[nE + i];
    int s = ei[i];
    if ((unsigned)d < (unsigned)n) {
      int pos = atomicAdd(&cur[d >> 8], 1);
      buf[pos] = ((unsigned)s << 8) | (unsigned)(d & 255);
    }
  }
  __syncthreads();
  int cnt = src[NB - 1];
  for (int i = t; i < cnt; i += 256) part[e0 + i] = buf[i];
}

// ---------------- GEMM tile body: MFMA fp16, fused alpha ----------------
template <typename T>
__device__ inline void gemm_tile(uint4* Xs, uint4* Ws, int t, int row0,
                                 const T* __restrict__ X, const float* __restrict__ W,
                                 const float* __restrict__ a_src,
                                 const float* __restrict__ a_dst,
                                 __half* __restrict__ H16,
                                 float* __restrict__ as_, float* __restrict__ ad_,
                                 int nrows) {
#pragma unroll
  for (int i = 0; i < 4; ++i) {
    int idx = t + i * 256;
    int r = idx >> 4;
    int j = idx & 15;
    uint4 u = make_uint4(0u, 0u, 0u, 0u);
    if (row0 + r < nrows) u = load8h(&X[(size_t)(row0 + r) * 128 + j * 8]);
    Xs[r * 16 + (j ^ (r & 15))] = u;
  }
#pragma unroll
  for (int i = 0; i < 8; ++i) {
    int idx = t + i * 256;
    int c = idx >> 4;
    int j = idx & 15;
    Ws[c * 16 + (j ^ (c & 15))] = load8h(&W[(size_t)c * 128 + j * 8]);
  }
  __syncthreads();

  int w = t >> 6;
  int lane = t & 63;
  int li = lane & 15;
  int quad = lane >> 4;

  v4f acc[8];
#pragma unroll
  for (int ct = 0; ct < 8; ++ct) acc[ct] = (v4f){0.f, 0.f, 0.f, 0.f};

#pragma unroll
  for (int kk = 0; kk < 4; ++kk) {
    int ch = kk * 4 + quad;
    union { uint4 u; v8h h; } av;
    av.u = Xs[(w * 16 + li) * 16 + (ch ^ li)];
#pragma unroll
    for (int ct = 0; ct < 8; ++ct) {
      union { uint4 u; v8h h; } bv;
      bv.u = Ws[(ct * 16 + li) * 16 + (ch ^ li)];
      acc[ct] = __builtin_amdgcn_mfma_f32_16x16x32_f16(av.h, bv.h, acc[ct], 0, 0, 0);
    }
  }

  float asum[4] = {0.f, 0.f, 0.f, 0.f};
  float adsum[4] = {0.f, 0.f, 0.f, 0.f};
#pragma unroll
  for (int ct = 0; ct < 8; ++ct) {
    float sa = a_src[ct * 16 + li];
    float da = a_dst[ct * 16 + li];
#pragma unroll
    for (int reg = 0; reg < 4; ++reg) {
      asum[reg] = fmaf(acc[ct][reg], sa, asum[reg]);
      adsum[reg] = fmaf(acc[ct][reg], da, adsum[reg]);
    }
  }
#pragma unroll
  for (int reg = 0; reg < 4; ++reg) {
    asum[reg] = sum16(asum[reg]);
    adsum[reg] = sum16(adsum[reg]);
  }
  if (li == 0) {
#pragma unroll
    for (int reg = 0; reg < 4; ++reg) {
      int r = row0 + w * 16 + quad * 4 + reg;
      if (r < nrows) {
        as_[r] = asum[reg];
        ad_[r] = adsum[reg];
      }
    }
  }

#pragma unroll
  for (int ct = 0; ct < 8; ++ct) {
#pragma unroll
    for (int reg = 0; reg < 4; ++reg) {
      float v0 = acc[ct][reg];
      float v1 = __shfl_xor(v0, 1);
      if (!(li & 1)) {
        int r = row0 + w * 16 + quad * 4 + reg;
        if (r < nrows) {
          __half2 hh = __floats2half2_rn(v0, v1);
          *(__half2*)&H16[(size_t)r * 128 + ct * 16 + li] = hh;
        }
      }
    }
  }
}

// ---------------- fused: partition blocks [0,PB) || layer-1 GEMM blocks [PB,..) ----------------
__global__ __launch_bounds__(256) void k_fused1(const int* __restrict__ ei,
                                                int* __restrict__ blkoff,
                                                unsigned* __restrict__ part,
                                                int nE, int n, int PB, int NB,
                                                const float* __restrict__ X,
                                                const float* __restrict__ W,
                                                const float* __restrict__ a_src,
                                                const float* __restrict__ a_dst,
                                                __half* __restrict__ H16,
                                                float* __restrict__ as_,
                                                float* __restrict__ ad_) {
  __shared__ __align__(16) char smraw[48 * 1024];
  int t = threadIdx.x;
  if ((int)blockIdx.x < PB) {
    psort_body(ei, blkoff, part, smraw, blockIdx.x, t, nE, n, NB);
  } else {
    uint4* Xs = (uint4*)smraw;            // 16 KB
    uint4* Ws = (uint4*)(smraw + 16384);  // 32 KB
    int row0 = (blockIdx.x - PB) * 64;
    gemm_tile<float>(Xs, Ws, t, row0, X, W, a_src, a_dst, H16, as_, ad_, n);
  }
}

// ---------------- standalone layer-2 GEMM ----------------
__global__ __launch_bounds__(256) void k_linear2(const __half* __restrict__ X,
                                                 const float* __restrict__ W,
                                                 const float* __restrict__ a_src,
                                                 const float* __restrict__ a_dst,
                                                 __half* __restrict__ H16,
                                                 float* __restrict__ as_,
                                                 float* __restrict__ ad_, int nrows) {
  __shared__ __align__(16) char smraw[48 * 1024];
  uint4* Xs = (uint4*)smraw;
  uint4* Ws = (uint4*)(smraw + 16384);
  gemm_tile<__half>(Xs, Ws, threadIdx.x, blockIdx.x * 64, X, W, a_src, a_dst,
                    H16, as_, ad_, nrows);
}

// ---------------- bucket: gather per-block runs, build CSR in LDS, write coalesced ----------------
__global__ __launch_bounds__(256) void k_bucket(const unsigned* __restrict__ part,
                                                const int* __restrict__ blkoff,
                                                int* __restrict__ rowptr,
                                                int* __restrict__ col,
                                                int PB, int NB, int n) {
  __shared__ int sdeg[256];
  __shared__ int sscan[256];
  __shared__ int pbeg[256];
  __shared__ int pend[256];
  __shared__ int red[256];
  __shared__ int lcol[8448];
  int b = blockIdx.x, t = threadIdx.x;
  int node0 = b * BPB;

  int lb = 0, le = 0;
  if (t < PB) {
    lb = blkoff[(size_t)t * (NB + 1) + b];
    le = blkoff[(size_t)t * (NB + 1) + b + 1];
  }
  pbeg[t] = lb;
  pend[t] = le;
  red[t] = lb;
  __syncthreads();
  for (int off = 128; off; off >>= 1) {
    if (t < off) red[t] += red[t + off];
    __syncthreads();
  }
  int ebeg = red[0];
  __syncthreads();
  red[t] = le - lb;
  __syncthreads();
  for (int off = 128; off; off >>= 1) {
    if (t < off) red[t] += red[t + off];
    __syncthreads();
  }
  int cnt = red[0];
  __syncthreads();
  if (cnt > 8192) cnt = 8192;  // >60-sigma guard (never triggers)

  int nloc = n - node0;
  if (nloc > BPB) nloc = BPB;

  sdeg[t] = (t < nloc) ? 1 : 0;  // self-loop
  __syncthreads();
  if (t < PB) {
    const unsigned* base = part + (size_t)t * EPB;
    for (int j = pbeg[t]; j < pend[t]; ++j) atomicAdd(&sdeg[base[j] & 255u], 1);
  }
  __syncthreads();
  int v = sdeg[t];
  sscan[t] = v;
  __syncthreads();
  for (int off = 1; off < 256; off <<= 1) {
    int x = (t >= off) ? sscan[t - off] : 0;
    __syncthreads();
    sscan[t] += x;
    __syncthreads();
  }
  int excl = sscan[t] - v;
  int gbase = ebeg + node0;
  if (t < nloc) rowptr[node0 + t] = gbase + excl;
  if (b == NB - 1 && t == 0) rowptr[n] = ebeg + cnt + n;
  if (t < nloc) lcol[excl] = node0 + t;  // self-loop entry first
  sdeg[t] = excl + 1;                    // cursor
  __syncthreads();
  if (t < PB) {
    const unsigned* base = part + (size_t)t * EPB;
    for (int j = pbeg[t]; j < pend[t]; ++j) {
      unsigned e = base[j];
      int pos = atomicAdd(&sdeg[e & 255u], 1);
      lcol[pos] = (int)(e >> 8);
    }
  }
  __syncthreads();
  int T = cnt + nloc;
  for (int i = t; i < T; i += 256) col[gbase + i] = lcol[i];
}

// ---------------- GAT aggregation: 16 lanes/node, 4 nodes/wave ----------------
// 8-deep prefetch in NAMED uint4 regs (q0..q7): probe for latency-limited vs
// L3-BW-limited gather (R12 post-mortem). Dynamic-indexed arrays would be
// LDS-promoted (R4: 201us regression) -> named regs + unroll-by-8.
#define AGG_SLOT(K, QREG)                                                  \
  if (K == 0 || jj + K < trips) {                                          \
    float wj = __shfl(wgt, gb | (jj + K));                                 \
    uint4 cur = QREG;                                                      \
    if (jj + K + 8 < trips) {                                              \
      int sq = __shfl(s, gb | (jj + K + 8));                               \
      QREG = *(const uint4*)(h + (size_t)sq * 128 + li * 8);               \
    }                                                                      \
    float2 f0 = __half22float2(*(__half2*)&cur.x);                         \
    float2 f1 = __half22float2(*(__half2*)&cur.y);                         \
    float2 f2 = __half22float2(*(__half2*)&cur.z);                         \
    float2 f3 = __half22float2(*(__half2*)&cur.w);                         \
    acc0 = fmaf(f0.x, wj, acc0); acc1 = fmaf(f0.y, wj, acc1);              \
    acc2 = fmaf(f1.x, wj, acc2); acc3 = fmaf(f1.y, wj, acc3);              \
    acc4 = fmaf(f2.x, wj, acc4); acc5 = fmaf(f2.y, wj, acc5);              \
    acc6 = fmaf(f3.x, wj, acc6); acc7 = fmaf(f3.y, wj, acc7);              \
  }

template <bool HEADS>
__global__ __launch_bounds__(256) void k_agg_t(const __half* __restrict__ h,
                                               const float* __restrict__ as_,
                                               const float* __restrict__ ad_,
                                               const int* __restrict__ rowptr,
                                               const int* __restrict__ col,
                                               const float* __restrict__ bias,
                                               void* __restrict__ outp,
                                               const float* __restrict__ Wf,
                                               const float* __restrict__ bf,
                                               const float* __restrict__ Wsk,
                                               const float* __restrict__ bs,
                                               int n) {
  int gid = blockIdx.x * 256 + threadIdx.x;
  int wid = gid >> 6;
  int lane = gid & 63;
  int g = lane >> 4;
  int li = lane & 15;
  int gb = lane & 48;
  int node = wid * 4 + g;
  bool valid = node < n;
  int beg = 0, end = 0;
  float adv = 0.f;
  if (valid) {
    beg = rowptr[node];
    end = rowptr[node + 1];
    adv = ad_[node];
  }
  int deg = end - beg;
  int md = deg;
  md = max(md, __shfl_xor(md, 16));
  md = max(md, __shfl_xor(md, 32));

  float acc0 = 0.f, acc1 = 0.f, acc2 = 0.f, acc3 = 0.f;
  float acc4 = 0.f, acc5 = 0.f, acc6 = 0.f, acc7 = 0.f;
  float den_l = 0.f;

  for (int base = 0; base < md; base += 16) {
    int s = 0;
    float wgt = 0.f;
    if (base + li < deg) {
      s = col[beg + base + li];
      if ((unsigned)s >= (unsigned)n) s = 0;
      float v = as_[s] + adv;
      v = (v > 0.f) ? v : 0.2f * v;
      wgt = __expf(v);
    }
    den_l += wgt;

    int rem = md - base;
    int trips = rem > 16 ? 16 : rem;  // wave-uniform
    uint4 q0 = make_uint4(0u, 0u, 0u, 0u);
    uint4 q1 = q0, q2 = q0, q3 = q0, q4 = q0, q5 = q0, q6 = q0, q7 = q0;
    {
      int sq = __shfl(s, gb);
      q0 = *(const uint4*)(h + (size_t)sq * 128 + li * 8);
      if (trips > 1) { sq = __shfl(s, gb | 1); q1 = *(const uint4*)(h + (size_t)sq * 128 + li * 8); }
      if (trips > 2) { sq = __shfl(s, gb | 2); q2 = *(const uint4*)(h + (size_t)sq * 128 + li * 8); }
      if (trips > 3) { sq = __shfl(s, gb | 3); q3 = *(const uint4*)(h + (size_t)sq * 128 + li * 8); }
      if (trips > 4) { sq = __shfl(s, gb | 4); q4 = *(const uint4*)(h + (size_t)sq * 128 + li * 8); }
      if (trips > 5) { sq = __shfl(s, gb | 5); q5 = *(const uint4*)(h + (size_t)sq * 128 + li * 8); }
      if (trips > 6) { sq = __shfl(s, gb | 6); q6 = *(const uint4*)(h + (size_t)sq * 128 + li * 8); }
      if (trips > 7) { sq = __shfl(s, gb | 7); q7 = *(const uint4*)(h + (size_t)sq * 128 + li * 8); }
    }
    for (int jj = 0; jj < trips; jj += 8) {
      AGG_SLOT(0, q0)
      AGG_SLOT(1, q1)
      AGG_SLOT(2, q2)
      AGG_SLOT(3, q3)
      AGG_SLOT(4, q4)
      AGG_SLOT(5, q5)
      AGG_SLOT(6, q6)
      AGG_SLOT(7, q7)
    }
  }

  float den = sum16(den_l);
  float inv = 1.0f / den;

  float4 bv0 = *(const float4*)&bias[li * 8];
  float4 bv1 = *(const float4*)&bias[li * 8 + 4];
  float o0 = fmaxf(fmaf(acc0, inv, bv0.x), 0.f);
  float o1 = fmaxf(fmaf(acc1, inv, bv0.y), 0.f);
  float o2 = fmaxf(fmaf(acc2, inv, bv0.z), 0.f);
  float o3 = fmaxf(fmaf(acc3, inv, bv0.w), 0.f);
  float o4 = fmaxf(fmaf(acc4, inv, bv1.x), 0.f);
  float o5 = fmaxf(fmaf(acc5, inv, bv1.y), 0.f);
  float o6 = fmaxf(fmaf(acc6, inv, bv1.z), 0.f);
  float o7 = fmaxf(fmaf(acc7, inv, bv1.w), 0.f);

  if (!HEADS) {
    if (valid) {
      union { __half2 h2[4]; uint4 u; } pk;
      pk.h2[0] = __floats2half2_rn(o0, o1);
      pk.h2[1] = __floats2half2_rn(o2, o3);
      pk.h2[2] = __floats2half2_rn(o4, o5);
      pk.h2[3] = __floats2half2_rn(o6, o7);
      *(uint4*)&(((__half*)outp)[(size_t)node * 128 + li * 8]) = pk.u;
    }
  } else {
    float p[10];
#pragma unroll
    for (int j = 0; j < 3; ++j) {
      float4 w0 = *(const float4*)&Wf[(size_t)j * 128 + li * 8];
      float4 w1 = *(const float4*)&Wf[(size_t)j * 128 + li * 8 + 4];
      p[j] = o0 * w0.x + o1 * w0.y + o2 * w0.z + o3 * w0.w +
             o4 * w1.x + o5 * w1.y + o6 * w1.z + o7 * w1.w;
    }
#pragma unroll
    for (int j = 0; j < 7; ++j) {
      float4 w0 = *(const float4*)&Wsk[(size_t)j * 128 + li * 8];
      float4 w1 = *(const float4*)&Wsk[(size_t)j * 128 + li * 8 + 4];
      p[3 + j] = o0 * w0.x + o1 * w0.y + o2 * w0.z + o3 * w0.w +
                 o4 * w1.x + o5 * w1.y + o6 * w1.z + o7 * w1.w;
    }
#pragma unroll
    for (int j = 0; j < 10; ++j) p[j] = sum16(p[j]);
    if (li == 0 && valid) {
      float* out = (float*)outp;
#pragma unroll
      for (int j = 0; j < 3; ++j) out[(size_t)node * 3 + j] = p[j] + bf[j];
      float* sk = out + (size_t)n * 3;
#pragma unroll
      for (int j = 0; j < 7; ++j) sk[(size_t)node * 7 + j] = p[3 + j] + bs[j];
    }
  }
}

// ---------------- launch ----------------
extern "C" void kernel_launch(void* const* d_in, const int* in_sizes, int n_in,
                              void* d_out, int out_size, void* d_ws, size_t ws_size,
                              hipStream_t stream) {
  const float* x = (const float*)d_in[0];
  const int* ei = (const int*)d_in[1];  // [2, E] int32
  const float* W1 = (const float*)d_in[2];
  const float* a_src1 = (const float*)d_in[3];
  const float* a_dst1 = (const float*)d_in[4];
  const float* b1 = (const float*)d_in[5];
  const float* W2 = (const float*)d_in[6];
  const float* a_src2 = (const float*)d_in[7];
  const float* a_dst2 = (const float*)d_in[8];
  const float* b2 = (const float*)d_in[9];
  const float* Wf = (const float*)d_in[10];
  const float* bf = (const float*)d_in[11];
  const float* Wsk = (const float*)d_in[12];
  const float* bs = (const float*)d_in[13];
  float* out = (float*)d_out;

  const int N = in_sizes[0] / 128;
  const int nE = in_sizes[1] / 2;
  const int NB = (N + BPB - 1) / BPB;   // buckets, <=512
  const int PB = (nE + EPB - 1) / EPB;  // partition blocks, <=256 for nE<=2M

  char* w = (char*)d_ws;
  auto carve = [&](size_t bytes) {
    char* p = w;
    w += (bytes + 255) & ~(size_t)255;
    return (void*)p;
  };
  __half* H16 = (__half*)carve((size_t)N * 128 * 2);  // GEMM out (row-major fp16)
  __half* B16 = (__half*)carve((size_t)N * 128 * 2);  // layer-1 agg out
  float* as_ = (float*)carve((size_t)N * 4);
  float* ad_ = (float*)carve((size_t)N * 4);
  int* rowptr = (int*)carve((size_t)(N + 1) * 4);
  int* col = (int*)carve((size_t)(nE + N) * 4);
  int* blkoff = (int*)carve((size_t)PB * (NB + 1) * 4);  // per-block local excl offsets
  unsigned* part = (unsigned*)carve((size_t)nE * 4);     // packed (src<<8)|dloc

  dim3 b256(256);
  const int gemm_blocks = (N + 63) / 64;
  const int agg_blocks = (((N + 3) / 4) * 64 + 255) / 256;  // 4 nodes/wave

  // ---- partition (block-local, coalesced) fused with layer-1 GEMM ----
  k_fused1<<<PB + gemm_blocks, b256, 0, stream>>>(ei, blkoff, part, nE, N, PB, NB,
                                                  x, W1, a_src1, a_dst1, H16, as_, ad_);
  k_bucket<<<NB, b256, 0, stream>>>(part, blkoff, rowptr, col, PB, NB, N);

  // ---- layer 1 aggregation ----
  k_agg_t<false><<<agg_blocks, b256, 0, stream>>>(H16, as_, ad_, rowptr, col, b1, B16,
                                                  nullptr, nullptr, nullptr, nullptr, N);

  // ---- layer 2 + fused heads ----
  k_linear2<<<gemm_blocks, b256, 0, stream>>>(B16, W2, a_src2, a_dst2, H16, as_, ad_, N);
  k_agg_t<true><<<agg_blocks, b256, 0, stream>>>(H16, as_, ad_, rowptr, col, b2, out,
                                                 Wf, bf, Wsk, bs, N);
}